// Round 4
// baseline (20506.024 us; speedup 1.0000x reference)
//
#include <hip/hip_runtime.h>
#include <cstdint>

#define T_STEPS 128
#define BATCH   1024
#define D_INPUT 96
#define H_DIM   128
#define NWIN    163   // 121 full 7-frame windows + 6 prefix partials + 36 clipped partials

// window table: widx -> (start frame, length)
__device__ __forceinline__ void win_decode(int widx, int& start, int& len) {
    if (widx < 121)      { start = widx;        len = 7; }            // [w, w+6]
    else if (widx < 127) { start = 0;           len = widx - 120; }   // s=0 grow, len 1..6
    else { const int r = widx - 127; const int s = 1 + r / 6;
           len = 1 + r % 6;          start = 7 * s - 1; }             // s>=1 grow partials
}

// (t, s) -> widx, or -1 when the reference window is empty (cur1 == +0)
__device__ __forceinline__ int widx_for(int t, int s) {
    if (t >= 49) return t - 49 + 7 * s;                 // slide regime: full windows
    if (s == 0)  return 121 + min(5, t);                // [0, min(5,t)]
    const int st = 7 * s - 1;
    if (t < st) return -1;
    const int len = min(7, t - st + 1);
    return (len == 7) ? st : (127 + (s - 1) * 6 + (len - 1));
}

// ---------------------------------------------------------------------------
// kA: CUR1[widx][b][h] = seqFMA_{d}( wsum[d], Win[h][d] ) — bit-identical to
// round 3 (ascending-k frame adds, ascending-d single-acc fmaf), but
// cooperative: block = 16 b x 128 h; window sums staged once in LDS
// (xs[d*16+bq]); each thread does 4 b's per Win element fetched.
// ---------------------------------------------------------------------------
__global__ __launch_bounds__(256) void kA_wincur(const float* __restrict__ x,
                                                 const float* __restrict__ Win,
                                                 float* __restrict__ CUR1) {
    __shared__ float xs[D_INPUT * 16];                  // xs[d*16 + bq], 6 KB
    const int widx = blockIdx.x;
    const int b0   = blockIdx.y * 16;
    int start, len; win_decode(widx, start, len);
    const int tid = threadIdx.x;

    for (int e = tid; e < D_INPUT * 16; e += 256) {
        const int d = e % D_INPUT, bq = e / D_INPUT;    // consecutive e -> consecutive d
        const float* xp = x + ((size_t)start * BATCH + b0 + bq) * D_INPUT + d;
        float s = xp[0];
        for (int k = 1; k < len; ++k)                   // ascending frame order (exact)
            s = __fadd_rn(s, xp[(size_t)k * BATCH * D_INPUT]);
        xs[d * 16 + bq] = s;
    }
    __syncthreads();

    const int hp = tid & 63, g = tid >> 6;              // h-pair, b-quad (g uniform/wave)
    const int h0 = hp << 1;
    const float* w0 = Win + (size_t)h0 * D_INPUT;
    const float* w1 = w0 + D_INPUT;
    float a00=0.f,a01=0.f,a10=0.f,a11=0.f,a20=0.f,a21=0.f,a30=0.f,a31=0.f;
#pragma unroll 8
    for (int d = 0; d < D_INPUT; ++d) {                 // ascending d, one acc each (exact)
        const float4 xv = *(const float4*)&xs[d * 16 + g * 4];   // LDS broadcast
        const float f0 = w0[d], f1 = w1[d];
        a00 = __fmaf_rn(xv.x, f0, a00); a01 = __fmaf_rn(xv.x, f1, a01);
        a10 = __fmaf_rn(xv.y, f0, a10); a11 = __fmaf_rn(xv.y, f1, a11);
        a20 = __fmaf_rn(xv.z, f0, a20); a21 = __fmaf_rn(xv.z, f1, a21);
        a30 = __fmaf_rn(xv.w, f0, a30); a31 = __fmaf_rn(xv.w, f1, a31);
    }
    float* op = CUR1 + ((size_t)widx * BATCH + b0 + g * 4) * H_DIM + h0;
    float2 o;
    o.x = a00; o.y = a01; *(float2*)(op              ) = o;
    o.x = a10; o.y = a11; *(float2*)(op +     H_DIM  ) = o;
    o.x = a20; o.y = a21; *(float2*)(op + 2 * H_DIM  ) = o;
    o.x = a30; o.y = a31; *(float2*)(op + 3 * H_DIM  ) = o;
}

// ---------------------------------------------------------------------------
// kB: 7 SNN steps, 4 (t,b) pairs in lockstep per wave, 16 waves/block sharing
// one 64 KB W_h0 table (lw[h*128+i]). cur2 accumulation is a DENSE unrolled
// fma chain over h=0..127 with spike floats in {0.0f,1.0f} extracted from the
// ballot masks on the scalar pipe — bit-identical to the ascending-h
// conditional __fadd_rn walk, but statically addressed (pipelined ds_reads).
// Linear tail (W_out / mem_out) relaxed to per-lane Horner + butterfly reduce.
// ---------------------------------------------------------------------------
__global__ __launch_bounds__(1024, 4) void kB_snn(const float* __restrict__ CUR1,
                                                  const float* __restrict__ Wh0,
                                                  const float* __restrict__ Wout,
                                                  const float* __restrict__ vxp,
                                                  const float* __restrict__ vyp,
                                                  float* __restrict__ out) {
    __shared__ float lw[H_DIM * H_DIM];                 // lw[h*128 + i] = Wh0[i][h]
    const int tid = threadIdx.x;
    for (int e = tid; e < H_DIM * H_DIM; e += 1024) {
        const int i = e >> 7, h = e & 127;              // Wh0 flat = i*128 + h
        lw[h * H_DIM + i] = Wh0[e];                     // one-time strided write
    }
    __syncthreads();

    const int w = tid >> 6, lane = tid & 63;
    const int t  = blockIdx.y;
    const int i0 = lane << 1;
    const float wex = Wout[i0],     wey = Wout[H_DIM + i0];
    const float wox = Wout[i0 + 1], woy = Wout[H_DIM + i0 + 1];
    const float vx = vxp[0], vy = vyp[0];
    const int b0 = (blockIdx.x << 6) + (w << 2);        // 4 consecutive b per wave

    float m1a[4], m1b[4], m2a[4], m2b[4], poa[4], pob[4];
    float c1a[4], c1b[4];
    bool  s1a[4], s1b[4], s2a[4], s2b[4];
#pragma unroll
    for (int k = 0; k < 4; ++k) {
        m1a[k]=0.f; m1b[k]=0.f; m2a[k]=0.f; m2b[k]=0.f; poa[k]=0.f; pob[k]=0.f;
        s1a[k]=false; s1b[k]=false; s2a[k]=false; s2b[k]=false;
    }

    // prefetch cur1 for s = 0
    {
        const int wi = widx_for(t, 0);
#pragma unroll
        for (int k = 0; k < 4; ++k) {
            if (wi >= 0) {
                const float2 v = *(const float2*)
                    &CUR1[((size_t)wi * BATCH + b0 + k) * H_DIM + i0];
                c1a[k] = v.x; c1b[k] = v.y;
            } else { c1a[k] = 0.f; c1b[k] = 0.f; }
        }
    }

#pragma unroll 1
    for (int s = 0; s < 7; ++s) {
        // prefetch next step's cur1 (hides the ~900cyc HBM/L3 latency)
        float n1a[4], n1b[4];
        if (s < 6) {
            const int wi = widx_for(t, s + 1);
#pragma unroll
            for (int k = 0; k < 4; ++k) {
                if (wi >= 0) {
                    const float2 v = *(const float2*)
                        &CUR1[((size_t)wi * BATCH + b0 + k) * H_DIM + i0];
                    n1a[k] = v.x; n1b[k] = v.y;
                } else { n1a[k] = 0.f; n1b[k] = 0.f; }
            }
        } else {
#pragma unroll
            for (int k = 0; k < 4; ++k) { n1a[k] = 0.f; n1b[k] = 0.f; }
        }

        // ---- mem1 update + spikes (exact: rn(rn(0.9*m)+c), select-0 reset) --
        uint64_t me[4], mo[4];
#pragma unroll
        for (int k = 0; k < 4; ++k) {
            m1a[k] = s1a[k] ? 0.f : __fadd_rn(__fmul_rn(0.9f, m1a[k]), c1a[k]);
            m1b[k] = s1b[k] ? 0.f : __fadd_rn(__fmul_rn(0.9f, m1b[k]), c1b[k]);
            s1a[k] = m1a[k] > 0.5f; s1b[k] = m1b[k] > 0.5f;
            me[k] = __ballot(s1a[k]);                   // bit l -> h = 2l (uniform SGPR)
            mo[k] = __ballot(s1b[k]);                   // bit l -> h = 2l+1
        }

        // ---- dense cur2: ascending h, fma with {0,1} spike floats (exact) ---
        float c2a[4] = {0.f,0.f,0.f,0.f}, c2b[4] = {0.f,0.f,0.f,0.f};
#pragma unroll
        for (int j = 0; j < 64; ++j) {
            const float2 we = *(const float2*)&lw[(2*j    ) * H_DIM + i0];
            const float2 wo = *(const float2*)&lw[(2*j + 1) * H_DIM + i0];
#pragma unroll
            for (int k = 0; k < 4; ++k) {
                const float se = __uint_as_float(0x3f800000u * (uint32_t)((me[k] >> j) & 1));
                const float so = __uint_as_float(0x3f800000u * (uint32_t)((mo[k] >> j) & 1));
                c2a[k] = __fmaf_rn(se, we.x, c2a[k]);   // h = 2j
                c2b[k] = __fmaf_rn(se, we.y, c2b[k]);
                c2a[k] = __fmaf_rn(so, wo.x, c2a[k]);   // h = 2j+1
                c2b[k] = __fmaf_rn(so, wo.y, c2b[k]);
            }
        }

        // ---- mem2 + spikes (exact) and linear output tail (relaxed) ---------
#pragma unroll
        for (int k = 0; k < 4; ++k) {
            m2a[k] = s2a[k] ? 0.f : __fadd_rn(__fmul_rn(0.9f, m2a[k]), c2a[k]);
            m2b[k] = s2b[k] ? 0.f : __fadd_rn(__fmul_rn(0.9f, m2b[k]), c2b[k]);
            s2a[k] = m2a[k] > 0.5f; s2b[k] = m2b[k] > 0.5f;
            const float p0 = (s2a[k] ? wex : 0.f) + (s2b[k] ? wox : 0.f);
            const float p1 = (s2a[k] ? wey : 0.f) + (s2b[k] ? woy : 0.f);
            poa[k] = __fmaf_rn(0.9f, poa[k], p0);       // mem_out is linear: order-safe
            pob[k] = __fmaf_rn(0.9f, pob[k], p1);
            c1a[k] = n1a[k]; c1b[k] = n1b[k];
        }
    }

    // ---- reduce per-lane output partials, write -----------------------------
#pragma unroll
    for (int k = 0; k < 4; ++k) {
        float r0 = poa[k], r1 = pob[k];
#pragma unroll
        for (int off = 32; off > 0; off >>= 1) {
            r0 += __shfl_xor(r0, off);
            r1 += __shfl_xor(r1, off);
        }
        if (lane == 0) {
            float2 o;
            o.x = __fmul_rn(r0, vx);
            o.y = __fmul_rn(r1, vy);
            *(float2*)(out + ((size_t)t * BATCH + b0 + k) * 2) = o;
        }
    }
}

// ---------------------------------------------------------------------------
extern "C" void kernel_launch(void* const* d_in, const int* in_sizes, int n_in,
                              void* d_out, int out_size, void* d_ws, size_t ws_size,
                              hipStream_t stream) {
    const float* x    = (const float*)d_in[0];   // (128,1024,96)
    const float* Win  = (const float*)d_in[1];   // (128,96)
    const float* Wh0  = (const float*)d_in[2];   // (128,128)
    const float* Wout = (const float*)d_in[3];   // (2,128)
    const float* vx   = (const float*)d_in[4];   // (1,)
    const float* vy   = (const float*)d_in[5];   // (1,)
    float* out  = (float*)d_out;                 // (128,1024,2)
    float* CUR1 = (float*)d_ws;                  // 163*1024*128*4 = 85.5 MB

    kA_wincur<<<dim3(NWIN, BATCH / 16), dim3(256),  0, stream>>>(x, Win, CUR1);
    kB_snn   <<<dim3(BATCH / 64, T_STEPS), dim3(1024), 0, stream>>>(CUR1, Wh0, Wout, vx, vy, out);
}

// Round 5
// 1156.899 us; speedup vs baseline: 17.7250x; 17.7250x over previous
//
#include <hip/hip_runtime.h>
#include <cstdint>

#define T_STEPS 128
#define BATCH   1024
#define D_INPUT 96
#define H_DIM   128
#define NWIN    163   // 121 full 7-frame windows + 6 prefix partials + 36 clipped partials

// window table: widx -> (start frame, length)
__device__ __forceinline__ void win_decode(int widx, int& start, int& len) {
    if (widx < 121)      { start = widx;        len = 7; }            // [w, w+6]
    else if (widx < 127) { start = 0;           len = widx - 120; }   // s=0 grow, len 1..6
    else { const int r = widx - 127; const int s = 1 + r / 6;
           len = 1 + r % 6;          start = 7 * s - 1; }             // s>=1 grow partials
}

// (t, s) -> widx, or -1 when the reference window is empty (cur1 == +0)
__device__ __forceinline__ int widx_for(int t, int s) {
    if (t >= 49) return t - 49 + 7 * s;                 // slide regime: full windows
    if (s == 0)  return 121 + min(5, t);                // [0, min(5,t)]
    const int st = 7 * s - 1;
    if (t < st) return -1;
    const int len = min(7, t - st + 1);
    return (len == 7) ? st : (127 + (s - 1) * 6 + (len - 1));
}

// ---------------------------------------------------------------------------
// kA: CUR1[widx][b][h] = seqFMA_{d}( wsum[d], Win[h][d] ) — bit-identical to
// round 3 (ascending-k frame adds, ascending-d single-acc fmaf). Cooperative:
// block = 16 b x 128 h; window sums staged in LDS; 4 b per Win fetch.
// ---------------------------------------------------------------------------
__global__ __launch_bounds__(256) void kA_wincur(const float* __restrict__ x,
                                                 const float* __restrict__ Win,
                                                 float* __restrict__ CUR1) {
    __shared__ float xs[D_INPUT * 16];                  // xs[d*16 + bq], 6 KB
    const int widx = blockIdx.x;
    const int b0   = blockIdx.y * 16;
    int start, len; win_decode(widx, start, len);
    const int tid = threadIdx.x;

    for (int e = tid; e < D_INPUT * 16; e += 256) {
        const int d = e % D_INPUT, bq = e / D_INPUT;
        const float* xp = x + ((size_t)start * BATCH + b0 + bq) * D_INPUT + d;
        float s = xp[0];
        for (int k = 1; k < len; ++k)                   // ascending frame order (exact)
            s = __fadd_rn(s, xp[(size_t)k * BATCH * D_INPUT]);
        xs[d * 16 + bq] = s;
    }
    __syncthreads();

    const int hp = tid & 63, g = tid >> 6;              // h-pair, b-quad (g uniform/wave)
    const int h0 = hp << 1;
    const float* w0 = Win + (size_t)h0 * D_INPUT;
    const float* w1 = w0 + D_INPUT;
    float a00=0.f,a01=0.f,a10=0.f,a11=0.f,a20=0.f,a21=0.f,a30=0.f,a31=0.f;
#pragma unroll 8
    for (int d = 0; d < D_INPUT; ++d) {                 // ascending d, one acc each (exact)
        const float4 xv = *(const float4*)&xs[d * 16 + g * 4];   // LDS broadcast
        const float f0 = w0[d], f1 = w1[d];
        a00 = __fmaf_rn(xv.x, f0, a00); a01 = __fmaf_rn(xv.x, f1, a01);
        a10 = __fmaf_rn(xv.y, f0, a10); a11 = __fmaf_rn(xv.y, f1, a11);
        a20 = __fmaf_rn(xv.z, f0, a20); a21 = __fmaf_rn(xv.z, f1, a21);
        a30 = __fmaf_rn(xv.w, f0, a30); a31 = __fmaf_rn(xv.w, f1, a31);
    }
    float* op = CUR1 + ((size_t)widx * BATCH + b0 + g * 4) * H_DIM + h0;
    float2 o;
    o.x = a00; o.y = a01; *(float2*)(op            ) = o;
    o.x = a10; o.y = a11; *(float2*)(op +     H_DIM) = o;
    o.x = a20; o.y = a21; *(float2*)(op + 2 * H_DIM) = o;
    o.x = a30; o.y = a31; *(float2*)(op + 3 * H_DIM) = o;
}

// ---------------------------------------------------------------------------
// kB: 7 SNN steps, 4 (t,b) pairs per wave, 8 waves/block sharing the 64 KB
// W_h0 table lw[h*128+i]. cur2 = dense ascending-h fma chain with spike
// floats in {0.0f, 1.0f} built from the (wave-uniform, SGPR-resident) ballot
// masks on the scalar pipe — bit-identical to sgemm's conditional fmaf chain.
// __launch_bounds__(512,4): VGPR cap 128 (round 4's (1024,4) forced 64 ->
// 50 GB scratch spill). No software prefetch: 16 waves/CU hide L3 latency.
// Linear tail (W_out / mem_out) relaxed: per-lane Horner + butterfly reduce.
// ---------------------------------------------------------------------------
__global__ __launch_bounds__(512, 4) void kB_snn(const float* __restrict__ CUR1,
                                                 const float* __restrict__ Wh0,
                                                 const float* __restrict__ Wout,
                                                 const float* __restrict__ vxp,
                                                 const float* __restrict__ vyp,
                                                 float* __restrict__ out) {
    __shared__ float lw[H_DIM * H_DIM];                 // lw[h*128 + i] = Wh0[i][h]
    const int tid = threadIdx.x;
    for (int e = tid; e < H_DIM * H_DIM; e += 512) {
        const int i = e >> 7, h = e & 127;              // Wh0 flat = i*128 + h
        lw[h * H_DIM + i] = Wh0[e];                     // one-time (conflicts negligible)
    }
    __syncthreads();

    const int w = tid >> 6, lane = tid & 63;
    const int t  = blockIdx.y;
    const int i0 = lane << 1;
    const float wex = Wout[i0],     wey = Wout[H_DIM + i0];
    const float wox = Wout[i0 + 1], woy = Wout[H_DIM + i0 + 1];
    const float vx = vxp[0], vy = vyp[0];
    const int b0 = (blockIdx.x << 5) + (w << 2);        // 4 consecutive b per wave

    float m1a[4], m1b[4], m2a[4], m2b[4], poa[4], pob[4];
    bool  s1a[4], s1b[4], s2a[4], s2b[4];
#pragma unroll
    for (int k = 0; k < 4; ++k) {
        m1a[k]=0.f; m1b[k]=0.f; m2a[k]=0.f; m2b[k]=0.f; poa[k]=0.f; pob[k]=0.f;
        s1a[k]=false; s1b[k]=false; s2a[k]=false; s2b[k]=false;
    }

#pragma unroll 1
    for (int s = 0; s < 7; ++s) {
        // ---- load cur1 (mostly L2/L3 hits; 16 waves/CU hide latency) -------
        const int wi = widx_for(t, s);                  // wave-uniform
        uint64_t me[4], mo[4];
#pragma unroll
        for (int k = 0; k < 4; ++k) {
            float ca = 0.f, cb = 0.f;
            if (wi >= 0) {
                const float2 v = *(const float2*)
                    &CUR1[((size_t)wi * BATCH + b0 + k) * H_DIM + i0];
                ca = v.x; cb = v.y;
            }
            // mem1 = rn(rn(0.9*m)+c), select-0 reset (exact)
            m1a[k] = s1a[k] ? 0.f : __fadd_rn(__fmul_rn(0.9f, m1a[k]), ca);
            m1b[k] = s1b[k] ? 0.f : __fadd_rn(__fmul_rn(0.9f, m1b[k]), cb);
            s1a[k] = m1a[k] > 0.5f; s1b[k] = m1b[k] > 0.5f;
            me[k] = __ballot(s1a[k]);                   // bit l -> h = 2l   (SGPR pair)
            mo[k] = __ballot(s1b[k]);                   // bit l -> h = 2l+1
        }

        // ---- dense cur2: ascending h, fma with {0,1} spike floats (exact) ---
        float c2a[4] = {0.f,0.f,0.f,0.f}, c2b[4] = {0.f,0.f,0.f,0.f};
#pragma unroll 16
        for (int j = 0; j < 64; ++j) {
            const float2 we = *(const float2*)&lw[(2*j    ) * H_DIM + i0];
            const float2 wo = *(const float2*)&lw[(2*j + 1) * H_DIM + i0];
#pragma unroll
            for (int k = 0; k < 4; ++k) {
                const float se = __uint_as_float(0x3f800000u * (uint32_t)((me[k] >> j) & 1));
                const float so = __uint_as_float(0x3f800000u * (uint32_t)((mo[k] >> j) & 1));
                c2a[k] = __fmaf_rn(se, we.x, c2a[k]);   // h = 2j
                c2b[k] = __fmaf_rn(se, we.y, c2b[k]);
                c2a[k] = __fmaf_rn(so, wo.x, c2a[k]);   // h = 2j+1
                c2b[k] = __fmaf_rn(so, wo.y, c2b[k]);
            }
        }

        // ---- mem2 + spikes (exact) and linear output tail (relaxed) ---------
#pragma unroll
        for (int k = 0; k < 4; ++k) {
            m2a[k] = s2a[k] ? 0.f : __fadd_rn(__fmul_rn(0.9f, m2a[k]), c2a[k]);
            m2b[k] = s2b[k] ? 0.f : __fadd_rn(__fmul_rn(0.9f, m2b[k]), c2b[k]);
            s2a[k] = m2a[k] > 0.5f; s2b[k] = m2b[k] > 0.5f;
            const float p0 = (s2a[k] ? wex : 0.f) + (s2b[k] ? wox : 0.f);
            const float p1 = (s2a[k] ? wey : 0.f) + (s2b[k] ? woy : 0.f);
            poa[k] = __fmaf_rn(0.9f, poa[k], p0);       // mem_out is linear: order-safe
            pob[k] = __fmaf_rn(0.9f, pob[k], p1);
        }
    }

    // ---- reduce per-lane output partials, write -----------------------------
#pragma unroll
    for (int k = 0; k < 4; ++k) {
        float r0 = poa[k], r1 = pob[k];
#pragma unroll
        for (int off = 32; off > 0; off >>= 1) {
            r0 += __shfl_xor(r0, off);
            r1 += __shfl_xor(r1, off);
        }
        if (lane == 0) {
            float2 o;
            o.x = __fmul_rn(r0, vx);
            o.y = __fmul_rn(r1, vy);
            *(float2*)(out + ((size_t)t * BATCH + b0 + k) * 2) = o;
        }
    }
}

// ---------------------------------------------------------------------------
extern "C" void kernel_launch(void* const* d_in, const int* in_sizes, int n_in,
                              void* d_out, int out_size, void* d_ws, size_t ws_size,
                              hipStream_t stream) {
    const float* x    = (const float*)d_in[0];   // (128,1024,96)
    const float* Win  = (const float*)d_in[1];   // (128,96)
    const float* Wh0  = (const float*)d_in[2];   // (128,128)
    const float* Wout = (const float*)d_in[3];   // (2,128)
    const float* vx   = (const float*)d_in[4];   // (1,)
    const float* vy   = (const float*)d_in[5];   // (1,)
    float* out  = (float*)d_out;                 // (128,1024,2)
    float* CUR1 = (float*)d_ws;                  // 163*1024*128*4 = 85.5 MB

    kA_wincur<<<dim3(NWIN, BATCH / 16),  dim3(256), 0, stream>>>(x, Win, CUR1);
    kB_snn   <<<dim3(BATCH / 32, T_STEPS), dim3(512), 0, stream>>>(CUR1, Wh0, Wout, vx, vy, out);
}